// Round 1
// baseline (485.033 us; speedup 1.0000x reference)
//
#include <hip/hip_runtime.h>

// Problem constants (LEVEL=10)
constexpr int S  = 2048;
constexpr int HS = 1024;
constexpr int B  = 2;
constexpr int F  = 5;
constexpr int PL = HS * S;               // per-(b,f) x plane elements
constexpr int OD = F * PL;               // out stride per direction d
constexpr int WI = (HS - 2) * (S - 2);   // per-k w_inner plane elements

constexpr int NPLANE = B * F;            // 10
constexpr int INTERIOR_BLOCKS = 8 * 128 * NPLANE * 2;  // 20480

typedef float v4  __attribute__((ext_vector_type(4)));
typedef float v4u __attribute__((ext_vector_type(4), aligned(4)));

__device__ __forceinline__ void st_nt(float* p, v4 v) {
    __builtin_nontemporal_store(v, (v4*)p);
}
__device__ __forceinline__ v4 ldu(const float* p) {
    return *(const v4u*)p;
}

// ---------- scalar path: handles ANY (i,j) — verified in round 0 ----------
__device__ void scalar_point(
    int i, int j,
    const float* __restrict__ x, const float* __restrict__ poles,
    const float* __restrict__ w_inner, const float* __restrict__ w_east,
    const float* __restrict__ w_cn, const float* __restrict__ w_ne,
    const float* __restrict__ w_nne, const float* __restrict__ w_nw,
    const float* __restrict__ w_nww, const float* __restrict__ w_west,
    float* __restrict__ out)
{
    // zero borders: whole column 0, and row HS-1 cols 1..HS-1
    if (j == 0 || (i == HS - 1 && j < HS)) {
        for (int b = 0; b < B; ++b) {
#pragma unroll
            for (int f = 0; f < F; ++f) {
                float* ob = out + b * (4 * OD) + f * PL + i * S + j;
                ob[0] = 0.f; ob[OD] = 0.f; ob[2 * OD] = 0.f; ob[3 * OD] = 0.f;
            }
        }
        return;
    }

    // interior
    if (i > 0 && i < HS - 1 && j < S - 1) {
        const int wo = (i - 1) * (S - 2) + (j - 1);
        const float w0 = w_inner[wo];
        const float w1 = w_inner[wo + WI];
        const float w2 = w_inner[wo + 2 * WI];
        const float w3 = w_inner[wo + 3 * WI];
        const float w4 = w_inner[wo + 4 * WI];
        const float w5 = w_inner[wo + 5 * WI];
        const int rm = (i - 1) * S + j;
        const int rc = i * S + j;
        const int rp = (i + 1) * S + j;
        for (int b = 0; b < B; ++b) {
#pragma unroll
            for (int f = 0; f < F; ++f) {
                const float* xb = x + (b * F + f) * PL;
                const float xi = xb[rc];
                const float d0 = (xb[rm - 1] - xi) * w0;
                const float d1 = (xb[rp + 1] - xi) * w1;
                const float d2 = (xb[rm] - xi) * w2 + (xb[rc + 1] - xi) * w3;
                const float d3 = (xb[rc - 1] - xi) * w4 + (xb[rp] - xi) * w5;
                float* ob = out + b * (4 * OD) + f * PL + rc;
                ob[0] = d0; ob[OD] = d1; ob[2 * OD] = d2; ob[3 * OD] = d3;
            }
        }
        return;
    }

    if (i == 0) {
        if (j < HS) {
            // EAST: i=0, j in 1..HS-1
            const int t = j - 1;
            const float w0 = w_east[t];
            const float w1 = w_east[t + (HS - 1)];
            const float w2 = w_east[t + 2 * (HS - 1)];
            const float w3 = w_east[t + 3 * (HS - 1)];
            const float w4 = w_east[t + 4 * (HS - 1)];
            const float w5 = w_east[t + 5 * (HS - 1)];
            for (int b = 0; b < B; ++b) {
#pragma unroll
                for (int f = 0; f < F; ++f) {
                    const int fm = (f == 0) ? F - 1 : f - 1;
                    const float* xb  = x + (b * F + f) * PL;
                    const float* xmb = x + (b * F + fm) * PL;
                    const float xi = xb[j];
                    const float d0 = (xmb[(HS - 1) * S + HS + t] - xi) * w0;
                    const float d1 = (xb[S + 2 + t] - xi) * w1;
                    const float d2 = (xmb[(HS - 1) * S + HS + 1 + t] - xi) * w2
                                   + (xb[2 + t] - xi) * w3;
                    const float d3 = (xb[t] - xi) * w4 + (xb[S + 1 + t] - xi) * w5;
                    float* ob = out + b * (4 * OD) + f * PL + j;
                    ob[0] = d0; ob[OD] = d1; ob[2 * OD] = d2; ob[3 * OD] = d3;
                }
            }
        } else if (j == HS) {
            // CN
            const float w0 = w_cn[0], w1 = w_cn[1], w2 = w_cn[2], w3 = w_cn[3], w4 = w_cn[4];
            for (int b = 0; b < B; ++b) {
#pragma unroll
                for (int f = 0; f < F; ++f) {
                    const int fm = (f == 0) ? F - 1 : f - 1;
                    const float* xb  = x + (b * F + f) * PL;
                    const float* xmb = x + (b * F + fm) * PL;
                    const float xi = xb[HS];
                    const float d0 = (xmb[(HS - 1) * S + S - 1] - xi) * w0;
                    const float d1 = (xb[S + HS + 1] - xi) * w1;
                    const float d2 = (xb[HS + 1] - xi) * w2;
                    const float d3 = (xb[HS - 1] - xi) * w3 + (xb[S + HS] - xi) * w4;
                    float* ob = out + b * (4 * OD) + f * PL + HS;
                    ob[0] = d0; ob[OD] = d1; ob[2 * OD] = d2; ob[3 * OD] = d3;
                }
            }
        } else if (j < S - 1) {
            // NE: i=0, j in HS+1..S-2
            const int t = j - HS - 1;
            const float w0 = w_ne[t];
            const float w1 = w_ne[t + (HS - 2)];
            const float w2 = w_ne[t + 2 * (HS - 2)];
            const float w3 = w_ne[t + 3 * (HS - 2)];
            const float w4 = w_ne[t + 4 * (HS - 2)];
            const float w5 = w_ne[t + 5 * (HS - 2)];
            for (int b = 0; b < B; ++b) {
#pragma unroll
                for (int f = 0; f < F; ++f) {
                    const int fm = (f == 0) ? F - 1 : f - 1;
                    const float* xb  = x + (b * F + f) * PL;
                    const float* xmb = x + (b * F + fm) * PL;
                    const float xi = xb[j];
                    const float d0 = (xmb[(HS - 2 - t) * S + S - 1] - xi) * w0
                                   + (xmb[(HS - 1 - t) * S + S - 1] - xi) * w1;
                    const float d1 = (xb[S + HS + 2 + t] - xi) * w2
                                   + (xb[S + HS + 1 + t] - xi) * w3;
                    const float d2 = (xb[HS + 2 + t] - xi) * w4;
                    const float d3 = (xb[HS + t] - xi) * w5;
                    float* ob = out + b * (4 * OD) + f * PL + j;
                    ob[0] = d0; ob[OD] = d1; ob[2 * OD] = d2; ob[3 * OD] = d3;
                }
            }
        } else {
            // NNE: i=0, j=S-1
            const float w0 = w_nne[0], w1 = w_nne[1], w2 = w_nne[2],
                        w3 = w_nne[3], w4 = w_nne[4], w5 = w_nne[5];
            for (int b = 0; b < B; ++b) {
#pragma unroll
                for (int f = 0; f < F; ++f) {
                    const int fm = (f == 0) ? F - 1 : f - 1;
                    const int fp = (f == F - 1) ? 0 : f + 1;
                    const float* xb  = x + (b * F + f) * PL;
                    const float* xmb = x + (b * F + fm) * PL;
                    const float* xpb = x + (b * F + fp) * PL;
                    const float xi = xb[S - 1];
                    const float d0 = (xmb[S - 1] - xi) * w0 + (xmb[S + S - 1] - xi) * w1;
                    const float d1 = (xpb[S - 1] - xi) * w2 + (xb[S + S - 1] - xi) * w3;
                    const float d2 = (poles[b * 2 + 1] - xi) * w4;
                    const float d3 = (xb[S - 2] - xi) * w5;
                    float* ob = out + b * (4 * OD) + f * PL + (S - 1);
                    ob[0] = d0; ob[OD] = d1; ob[2 * OD] = d2; ob[3 * OD] = d3;
                }
            }
        }
        return;
    }

    if (i == HS - 1) {
        if (j < S - 1) {
            // WEST: i=HS-1, j in HS..S-2
            const int t = j - HS;
            const float w0 = w_west[t];
            const float w1 = w_west[t + (HS - 1)];
            const float w2 = w_west[t + 2 * (HS - 1)];
            const float w3 = w_west[t + 3 * (HS - 1)];
            const float w4 = w_west[t + 4 * (HS - 1)];
            const float w5 = w_west[t + 5 * (HS - 1)];
            for (int b = 0; b < B; ++b) {
#pragma unroll
                for (int f = 0; f < F; ++f) {
                    const int fp = (f == F - 1) ? 0 : f + 1;
                    const float* xb  = x + (b * F + f) * PL;
                    const float* xpb = x + (b * F + fp) * PL;
                    const float xi = xb[(HS - 1) * S + j];
                    const float d0 = (xb[(HS - 2) * S + HS - 1 + t] - xi) * w0;
                    const float d1 = (xpb[1 + t] - xi) * w1;
                    const float d2 = (xb[(HS - 2) * S + HS + t] - xi) * w2
                                   + (xb[(HS - 1) * S + HS + 1 + t] - xi) * w3;
                    const float d3 = (xb[(HS - 1) * S + HS - 1 + t] - xi) * w4
                                   + (xpb[t] - xi) * w5;
                    float* ob = out + b * (4 * OD) + f * PL + (HS - 1) * S + j;
                    ob[0] = d0; ob[OD] = d1; ob[2 * OD] = d2; ob[3 * OD] = d3;
                }
            }
        } else {
            // NWW: i=HS-1, j=S-1
            const float w0 = w_nww[0], w1 = w_nww[1], w2 = w_nww[2],
                        w3 = w_nww[3], w4 = w_nww[4], w5 = w_nww[5];
            for (int b = 0; b < B; ++b) {
#pragma unroll
                for (int f = 0; f < F; ++f) {
                    const int fp = (f == F - 1) ? 0 : f + 1;
                    const float* xb  = x + (b * F + f) * PL;
                    const float* xpb = x + (b * F + fp) * PL;
                    const float xi = xb[(HS - 1) * S + S - 1];
                    const float d0 = (xb[(HS - 2) * S + S - 2] - xi) * w0;
                    const float d1 = (xpb[HS] - xi) * w1;
                    const float d2 = (xb[(HS - 2) * S + S - 1] - xi) * w2
                                   + (xpb[HS + 1] - xi) * w3;
                    const float d3 = (xb[(HS - 1) * S + S - 2] - xi) * w4
                                   + (xpb[HS - 1] - xi) * w5;
                    float* ob = out + b * (4 * OD) + f * PL + (HS - 1) * S + (S - 1);
                    ob[0] = d0; ob[OD] = d1; ob[2 * OD] = d2; ob[3 * OD] = d3;
                }
            }
        }
        return;
    }

    // NW: i in 1..HS-2, j=S-1
    {
        const int t = i - 1;
        const float w0 = w_nw[t];
        const float w1 = w_nw[t + (HS - 2)];
        const float w2 = w_nw[t + 2 * (HS - 2)];
        const float w3 = w_nw[t + 3 * (HS - 2)];
        const float w4 = w_nw[t + 4 * (HS - 2)];
        const float w5 = w_nw[t + 5 * (HS - 2)];
        for (int b = 0; b < B; ++b) {
#pragma unroll
            for (int f = 0; f < F; ++f) {
                const int fp = (f == F - 1) ? 0 : f + 1;
                const float* xb  = x + (b * F + f) * PL;
                const float* xpb = x + (b * F + fp) * PL;
                const float xi = xb[i * S + S - 1];
                const float d0 = (xb[(i - 1) * S + S - 2] - xi) * w0;
                const float d1 = (xpb[S - 2 - t] - xi) * w1;
                const float d2 = (xb[(i - 1) * S + S - 1] - xi) * w2
                               + (xpb[S - 1 - t] - xi) * w3;
                const float d3 = (xb[i * S + S - 2] - xi) * w4
                               + (xb[(i + 1) * S + S - 1] - xi) * w5;
                float* ob = out + b * (4 * OD) + f * PL + i * S + (S - 1);
                ob[0] = d0; ob[OD] = d1; ob[2 * OD] = d2; ob[3 * OD] = d3;
            }
        }
    }
}

// ---------- main kernel ----------
// Interior: grid split by XCD band AND (b,f) plane.
//   p < 20480: band = p&7 (XCD), idx = p>>3 in [0,2560):
//     row_in_band = idx/20, t = idx%20, plane = t>>1 (b*F+f), half = t&1.
//     i = band*128 + row_in_band + 1  (rows 1..1022 valid; 1023/1024 -> return)
//   Planes are INNERMOST in time on each XCD: consecutive blocks re-read the
//   same w_inner rows (x10) and the same 3-row x halo (x3) -> per-XCD L2 hits
//   (working set ~1.8 MB < 4 MB). Per-thread body: 13 loads, 4 NT stores,
//   ~50 VGPR -> 10x more waves than the old 10-plane-per-thread body.
// Blocks 20480..20527: scalar edge work (rows 0 & HS-1, cols 0..3 & 2044..2047).
__global__ __launch_bounds__(256)
void icok(const float* __restrict__ x, const float* __restrict__ poles,
          const float* __restrict__ w_inner, const float* __restrict__ w_east,
          const float* __restrict__ w_cn, const float* __restrict__ w_ne,
          const float* __restrict__ w_nne, const float* __restrict__ w_nw,
          const float* __restrict__ w_nww, const float* __restrict__ w_west,
          float* __restrict__ out)
{
    const int p = blockIdx.x;

    if (p < INTERIOR_BLOCKS) {
        const int band = p & 7;
        const int idx  = p >> 3;             // 0..2559
        const int rowb = idx / 20;           // 0..127
        const int t    = idx - rowb * 20;    // 0..19
        const int plane = t >> 1;            // 0..9 == b*F + f
        const int half  = t & 1;
        const int i = band * 128 + rowb + 1; // 1..1024
        if (i > HS - 2) return;              // rows 1023,1024 invalid
        const int jt = (half << 8) | threadIdx.x;    // 0..511
        if (jt == 0 || jt == 511) return;    // edge cols -> scalar blocks
        const int j0 = jt << 2;              // 4..2040

        const int wo = (i - 1) * (S - 2) + (j0 - 1);
        const v4 w0v = ldu(w_inner + wo);
        const v4 w1v = ldu(w_inner + wo + WI);
        const v4 w2v = ldu(w_inner + wo + 2 * WI);
        const v4 w3v = ldu(w_inner + wo + 3 * WI);
        const v4 w4v = ldu(w_inner + wo + 4 * WI);
        const v4 w5v = ldu(w_inner + wo + 5 * WI);

        const int rm = (i - 1) * S + j0;
        const int rc = i * S + j0;
        const int rp = (i + 1) * S + j0;

        const float* xb = x + plane * PL;
        const v4 c   = *(const v4*)(xb + rc);
        const v4 m   = *(const v4*)(xb + rm);
        const v4 pv  = *(const v4*)(xb + rp);
        const v4 mm1 = ldu(xb + rm - 1);     // x[i-1][j-1..j+2]
        const v4 cm1 = ldu(xb + rc - 1);     // x[i  ][j-1..j+2]
        const v4 cp1 = ldu(xb + rc + 1);     // x[i  ][j+1..j+4]
        const v4 pp1 = ldu(xb + rp + 1);     // x[i+1][j+1..j+4]

        const v4 d0 = (mm1 - c) * w0v;
        const v4 d1 = (pp1 - c) * w1v;
        const v4 d2 = (m - c) * w2v + (cp1 - c) * w3v;
        const v4 d3 = (cm1 - c) * w4v + (pv - c) * w5v;

        const int bb = (plane >= F) ? 1 : 0;
        const int ff = plane - bb * F;
        float* ob = out + bb * (4 * OD) + ff * PL + rc;
        st_nt(ob, d0);
        st_nt(ob + OD, d1);
        st_nt(ob + 2 * OD, d2);
        st_nt(ob + 3 * OD, d3);
        return;
    }

    // edge blocks
    const int e = (p - INTERIOR_BLOCKS) * 256 + threadIdx.x;
    int i, j;
    if (e < 2048)      { i = 0;      j = e; }
    else if (e < 4096) { i = HS - 1; j = e - 2048; }
    else if (e < 4096 + 8 * (HS - 2)) {
        const int t = e - 4096;
        i = 1 + (t >> 3);
        const int c = t & 7;
        j = (c < 4) ? c : (2040 + c);
    } else return;
    scalar_point(i, j, x, poles, w_inner, w_east, w_cn, w_ne, w_nne,
                 w_nw, w_nww, w_west, out);
}

extern "C" void kernel_launch(void* const* d_in, const int* in_sizes, int n_in,
                              void* d_out, int out_size, void* d_ws, size_t ws_size,
                              hipStream_t stream) {
    const float* x       = (const float*)d_in[0];
    const float* poles   = (const float*)d_in[1];
    const float* w_inner = (const float*)d_in[2];
    const float* w_east  = (const float*)d_in[3];
    const float* w_cn    = (const float*)d_in[4];
    const float* w_ne    = (const float*)d_in[5];
    const float* w_nne   = (const float*)d_in[6];
    const float* w_nw    = (const float*)d_in[7];
    const float* w_nww   = (const float*)d_in[8];
    const float* w_west  = (const float*)d_in[9];
    float* out = (float*)d_out;

    dim3 grid(INTERIOR_BLOCKS + 48), block(256);
    hipLaunchKernelGGL(icok, grid, block, 0, stream,
                       x, poles, w_inner, w_east, w_cn, w_ne, w_nne, w_nw,
                       w_nww, w_west, out);
}

// Round 2
// 464.091 us; speedup vs baseline: 1.0451x; 1.0451x over previous
//
#include <hip/hip_runtime.h>

// Problem constants (LEVEL=10)
constexpr int S  = 2048;
constexpr int HS = 1024;
constexpr int B  = 2;
constexpr int F  = 5;
constexpr int PL = HS * S;               // per-(b,f) x plane elements
constexpr int OD = F * PL;               // out stride per direction d
constexpr int WI = (HS - 2) * (S - 2);   // per-k w_inner plane elements

constexpr int NPLANE = B * F;            // 10
constexpr int EDGE_BLOCKS = 48;

typedef float v4  __attribute__((ext_vector_type(4)));
typedef float v4u __attribute__((ext_vector_type(4), aligned(4)));

__device__ __forceinline__ void st_nt(float* p, v4 v) {
    __builtin_nontemporal_store(v, (v4*)p);
}
__device__ __forceinline__ v4 ldu(const float* p) {
    return *(const v4u*)p;
}
__device__ __forceinline__ v4 ldu_nt(const float* p) {
    return __builtin_nontemporal_load((const v4u*)p);
}

// ---------- scalar path: handles ANY (i,j) — verified in round 0 ----------
__device__ void scalar_point(
    int i, int j,
    const float* __restrict__ x, const float* __restrict__ poles,
    const float* __restrict__ w_inner, const float* __restrict__ w_east,
    const float* __restrict__ w_cn, const float* __restrict__ w_ne,
    const float* __restrict__ w_nne, const float* __restrict__ w_nw,
    const float* __restrict__ w_nww, const float* __restrict__ w_west,
    float* __restrict__ out)
{
    // zero borders: whole column 0, and row HS-1 cols 1..HS-1
    if (j == 0 || (i == HS - 1 && j < HS)) {
        for (int b = 0; b < B; ++b) {
#pragma unroll
            for (int f = 0; f < F; ++f) {
                float* ob = out + b * (4 * OD) + f * PL + i * S + j;
                ob[0] = 0.f; ob[OD] = 0.f; ob[2 * OD] = 0.f; ob[3 * OD] = 0.f;
            }
        }
        return;
    }

    // interior
    if (i > 0 && i < HS - 1 && j < S - 1) {
        const int wo = (i - 1) * (S - 2) + (j - 1);
        const float w0 = w_inner[wo];
        const float w1 = w_inner[wo + WI];
        const float w2 = w_inner[wo + 2 * WI];
        const float w3 = w_inner[wo + 3 * WI];
        const float w4 = w_inner[wo + 4 * WI];
        const float w5 = w_inner[wo + 5 * WI];
        const int rm = (i - 1) * S + j;
        const int rc = i * S + j;
        const int rp = (i + 1) * S + j;
        for (int b = 0; b < B; ++b) {
#pragma unroll
            for (int f = 0; f < F; ++f) {
                const float* xb = x + (b * F + f) * PL;
                const float xi = xb[rc];
                const float d0 = (xb[rm - 1] - xi) * w0;
                const float d1 = (xb[rp + 1] - xi) * w1;
                const float d2 = (xb[rm] - xi) * w2 + (xb[rc + 1] - xi) * w3;
                const float d3 = (xb[rc - 1] - xi) * w4 + (xb[rp] - xi) * w5;
                float* ob = out + b * (4 * OD) + f * PL + rc;
                ob[0] = d0; ob[OD] = d1; ob[2 * OD] = d2; ob[3 * OD] = d3;
            }
        }
        return;
    }

    if (i == 0) {
        if (j < HS) {
            // EAST: i=0, j in 1..HS-1
            const int t = j - 1;
            const float w0 = w_east[t];
            const float w1 = w_east[t + (HS - 1)];
            const float w2 = w_east[t + 2 * (HS - 1)];
            const float w3 = w_east[t + 3 * (HS - 1)];
            const float w4 = w_east[t + 4 * (HS - 1)];
            const float w5 = w_east[t + 5 * (HS - 1)];
            for (int b = 0; b < B; ++b) {
#pragma unroll
                for (int f = 0; f < F; ++f) {
                    const int fm = (f == 0) ? F - 1 : f - 1;
                    const float* xb  = x + (b * F + f) * PL;
                    const float* xmb = x + (b * F + fm) * PL;
                    const float xi = xb[j];
                    const float d0 = (xmb[(HS - 1) * S + HS + t] - xi) * w0;
                    const float d1 = (xb[S + 2 + t] - xi) * w1;
                    const float d2 = (xmb[(HS - 1) * S + HS + 1 + t] - xi) * w2
                                   + (xb[2 + t] - xi) * w3;
                    const float d3 = (xb[t] - xi) * w4 + (xb[S + 1 + t] - xi) * w5;
                    float* ob = out + b * (4 * OD) + f * PL + j;
                    ob[0] = d0; ob[OD] = d1; ob[2 * OD] = d2; ob[3 * OD] = d3;
                }
            }
        } else if (j == HS) {
            // CN
            const float w0 = w_cn[0], w1 = w_cn[1], w2 = w_cn[2], w3 = w_cn[3], w4 = w_cn[4];
            for (int b = 0; b < B; ++b) {
#pragma unroll
                for (int f = 0; f < F; ++f) {
                    const int fm = (f == 0) ? F - 1 : f - 1;
                    const float* xb  = x + (b * F + f) * PL;
                    const float* xmb = x + (b * F + fm) * PL;
                    const float xi = xb[HS];
                    const float d0 = (xmb[(HS - 1) * S + S - 1] - xi) * w0;
                    const float d1 = (xb[S + HS + 1] - xi) * w1;
                    const float d2 = (xb[HS + 1] - xi) * w2;
                    const float d3 = (xb[HS - 1] - xi) * w3 + (xb[S + HS] - xi) * w4;
                    float* ob = out + b * (4 * OD) + f * PL + HS;
                    ob[0] = d0; ob[OD] = d1; ob[2 * OD] = d2; ob[3 * OD] = d3;
                }
            }
        } else if (j < S - 1) {
            // NE: i=0, j in HS+1..S-2
            const int t = j - HS - 1;
            const float w0 = w_ne[t];
            const float w1 = w_ne[t + (HS - 2)];
            const float w2 = w_ne[t + 2 * (HS - 2)];
            const float w3 = w_ne[t + 3 * (HS - 2)];
            const float w4 = w_ne[t + 4 * (HS - 2)];
            const float w5 = w_ne[t + 5 * (HS - 2)];
            for (int b = 0; b < B; ++b) {
#pragma unroll
                for (int f = 0; f < F; ++f) {
                    const int fm = (f == 0) ? F - 1 : f - 1;
                    const float* xb  = x + (b * F + f) * PL;
                    const float* xmb = x + (b * F + fm) * PL;
                    const float xi = xb[j];
                    const float d0 = (xmb[(HS - 2 - t) * S + S - 1] - xi) * w0
                                   + (xmb[(HS - 1 - t) * S + S - 1] - xi) * w1;
                    const float d1 = (xb[S + HS + 2 + t] - xi) * w2
                                   + (xb[S + HS + 1 + t] - xi) * w3;
                    const float d2 = (xb[HS + 2 + t] - xi) * w4;
                    const float d3 = (xb[HS + t] - xi) * w5;
                    float* ob = out + b * (4 * OD) + f * PL + j;
                    ob[0] = d0; ob[OD] = d1; ob[2 * OD] = d2; ob[3 * OD] = d3;
                }
            }
        } else {
            // NNE: i=0, j=S-1
            const float w0 = w_nne[0], w1 = w_nne[1], w2 = w_nne[2],
                        w3 = w_nne[3], w4 = w_nne[4], w5 = w_nne[5];
            for (int b = 0; b < B; ++b) {
#pragma unroll
                for (int f = 0; f < F; ++f) {
                    const int fm = (f == 0) ? F - 1 : f - 1;
                    const int fp = (f == F - 1) ? 0 : f + 1;
                    const float* xb  = x + (b * F + f) * PL;
                    const float* xmb = x + (b * F + fm) * PL;
                    const float* xpb = x + (b * F + fp) * PL;
                    const float xi = xb[S - 1];
                    const float d0 = (xmb[S - 1] - xi) * w0 + (xmb[S + S - 1] - xi) * w1;
                    const float d1 = (xpb[S - 1] - xi) * w2 + (xb[S + S - 1] - xi) * w3;
                    const float d2 = (poles[b * 2 + 1] - xi) * w4;
                    const float d3 = (xb[S - 2] - xi) * w5;
                    float* ob = out + b * (4 * OD) + f * PL + (S - 1);
                    ob[0] = d0; ob[OD] = d1; ob[2 * OD] = d2; ob[3 * OD] = d3;
                }
            }
        }
        return;
    }

    if (i == HS - 1) {
        if (j < S - 1) {
            // WEST: i=HS-1, j in HS..S-2
            const int t = j - HS;
            const float w0 = w_west[t];
            const float w1 = w_west[t + (HS - 1)];
            const float w2 = w_west[t + 2 * (HS - 1)];
            const float w3 = w_west[t + 3 * (HS - 1)];
            const float w4 = w_west[t + 4 * (HS - 1)];
            const float w5 = w_west[t + 5 * (HS - 1)];
            for (int b = 0; b < B; ++b) {
#pragma unroll
                for (int f = 0; f < F; ++f) {
                    const int fp = (f == F - 1) ? 0 : f + 1;
                    const float* xb  = x + (b * F + f) * PL;
                    const float* xpb = x + (b * F + fp) * PL;
                    const float xi = xb[(HS - 1) * S + j];
                    const float d0 = (xb[(HS - 2) * S + HS - 1 + t] - xi) * w0;
                    const float d1 = (xpb[1 + t] - xi) * w1;
                    const float d2 = (xb[(HS - 2) * S + HS + t] - xi) * w2
                                   + (xb[(HS - 1) * S + HS + 1 + t] - xi) * w3;
                    const float d3 = (xb[(HS - 1) * S + HS - 1 + t] - xi) * w4
                                   + (xpb[t] - xi) * w5;
                    float* ob = out + b * (4 * OD) + f * PL + (HS - 1) * S + j;
                    ob[0] = d0; ob[OD] = d1; ob[2 * OD] = d2; ob[3 * OD] = d3;
                }
            }
        } else {
            // NWW: i=HS-1, j=S-1
            const float w0 = w_nww[0], w1 = w_nww[1], w2 = w_nww[2],
                        w3 = w_nww[3], w4 = w_nww[4], w5 = w_nww[5];
            for (int b = 0; b < B; ++b) {
#pragma unroll
                for (int f = 0; f < F; ++f) {
                    const int fp = (f == F - 1) ? 0 : f + 1;
                    const float* xb  = x + (b * F + f) * PL;
                    const float* xpb = x + (b * F + fp) * PL;
                    const float xi = xb[(HS - 1) * S + S - 1];
                    const float d0 = (xb[(HS - 2) * S + S - 2] - xi) * w0;
                    const float d1 = (xpb[HS] - xi) * w1;
                    const float d2 = (xb[(HS - 2) * S + S - 1] - xi) * w2
                                   + (xpb[HS + 1] - xi) * w3;
                    const float d3 = (xb[(HS - 1) * S + S - 2] - xi) * w4
                                   + (xpb[HS - 1] - xi) * w5;
                    float* ob = out + b * (4 * OD) + f * PL + (HS - 1) * S + (S - 1);
                    ob[0] = d0; ob[OD] = d1; ob[2 * OD] = d2; ob[3 * OD] = d3;
                }
            }
        }
        return;
    }

    // NW: i in 1..HS-2, j=S-1
    {
        const int t = i - 1;
        const float w0 = w_nw[t];
        const float w1 = w_nw[t + (HS - 2)];
        const float w2 = w_nw[t + 2 * (HS - 2)];
        const float w3 = w_nw[t + 3 * (HS - 2)];
        const float w4 = w_nw[t + 4 * (HS - 2)];
        const float w5 = w_nw[t + 5 * (HS - 2)];
        for (int b = 0; b < B; ++b) {
#pragma unroll
            for (int f = 0; f < F; ++f) {
                const int fp = (f == F - 1) ? 0 : f + 1;
                const float* xb  = x + (b * F + f) * PL;
                const float* xpb = x + (b * F + fp) * PL;
                const float xi = xb[i * S + S - 1];
                const float d0 = (xb[(i - 1) * S + S - 2] - xi) * w0;
                const float d1 = (xpb[S - 2 - t] - xi) * w1;
                const float d2 = (xb[(i - 1) * S + S - 1] - xi) * w2
                               + (xpb[S - 1 - t] - xi) * w3;
                const float d3 = (xb[i * S + S - 2] - xi) * w4
                               + (xb[(i + 1) * S + S - 1] - xi) * w5;
                float* ob = out + b * (4 * OD) + f * PL + i * S + (S - 1);
                ob[0] = d0; ob[OD] = d1; ob[2 * OD] = d2; ob[3 * OD] = d3;
            }
        }
    }
}

// ---------- main kernel ----------
// Blocks 0..47: scalar edge work FIRST (overlaps interior; no tail).
// Blocks 48..2095: vector interior, q = p-48. XCD band swizzle:
//   l = (q&7)*256 + (q>>3); i = 1 + l/2 (rows 1..1022); 2 blocks/row.
// One thread = one j-quad ACROSS ALL 10 (b,f) planes: 6 w v4-loads (NT,
// zero-reuse stream) amortized 10x; per-plane body is 7 unaligned/aligned
// v4 x-loads + 4 NT v4 stores, rolled (#pragma unroll 1) to keep VGPR
// under the 128 tier -> 16 waves/CU.
__global__ __launch_bounds__(256)
void icok(const float* __restrict__ x, const float* __restrict__ poles,
          const float* __restrict__ w_inner, const float* __restrict__ w_east,
          const float* __restrict__ w_cn, const float* __restrict__ w_ne,
          const float* __restrict__ w_nne, const float* __restrict__ w_nw,
          const float* __restrict__ w_nww, const float* __restrict__ w_west,
          float* __restrict__ out)
{
    const int p = blockIdx.x;

    if (p >= EDGE_BLOCKS) {
        const int q = p - EDGE_BLOCKS;           // 0..2047 (48%8==0 keeps q%8 == p%8)
        const int l = ((q & 7) << 8) | (q >> 3);
        const int i = 1 + (l >> 1);              // row 1..1024
        if (i > HS - 2) return;                  // rows 1023,1024 invalid
        const int jt = ((l & 1) << 8) | threadIdx.x;   // 0..511
        if (jt == 0 || jt == 511) return;        // edge cols handled by edge blocks
        const int j0 = jt << 2;                  // 4..2040

        const int wo = (i - 1) * (S - 2) + (j0 - 1);
        const v4 w0v = ldu_nt(w_inner + wo);
        const v4 w1v = ldu_nt(w_inner + wo + WI);
        const v4 w2v = ldu_nt(w_inner + wo + 2 * WI);
        const v4 w3v = ldu_nt(w_inner + wo + 3 * WI);
        const v4 w4v = ldu_nt(w_inner + wo + 4 * WI);
        const v4 w5v = ldu_nt(w_inner + wo + 5 * WI);

        const int rm = (i - 1) * S + j0;
        const int rc = i * S + j0;
        const int rp = (i + 1) * S + j0;

        const float* xb = x + rc;                // advance by PL per plane
        float* ob = out + rc;                    // advance by PL (16*PL at b-boundary)

#pragma unroll 1
        for (int plane = 0; plane < NPLANE; ++plane) {
            const v4 c   = *(const v4*)(xb);
            const v4 m   = *(const v4*)(xb + (rm - rc));
            const v4 pv  = *(const v4*)(xb + (rp - rc));
            const v4 mm1 = ldu(xb + (rm - rc) - 1);   // x[i-1][j-1..j+2]
            const v4 cm1 = ldu(xb - 1);               // x[i  ][j-1..j+2]
            const v4 cp1 = ldu(xb + 1);               // x[i  ][j+1..j+4]
            const v4 pp1 = ldu(xb + (rp - rc) + 1);   // x[i+1][j+1..j+4]

            const v4 d0 = (mm1 - c) * w0v;
            const v4 d1 = (pp1 - c) * w1v;
            const v4 d2 = (m - c) * w2v + (cp1 - c) * w3v;
            const v4 d3 = (cm1 - c) * w4v + (pv - c) * w5v;

            st_nt(ob, d0);
            st_nt(ob + OD, d1);
            st_nt(ob + 2 * OD, d2);
            st_nt(ob + 3 * OD, d3);

            xb += PL;
            ob += (plane == F - 1) ? (4 * OD - (F - 1) * PL) : PL;  // b=0,f=4 -> b=1,f=0
        }
        return;
    }

    // edge blocks (p < 48)
    const int e = p * 256 + threadIdx.x;
    int i, j;
    if (e < 2048)      { i = 0;      j = e; }
    else if (e < 4096) { i = HS - 1; j = e - 2048; }
    else if (e < 4096 + 8 * (HS - 2)) {
        const int t = e - 4096;
        i = 1 + (t >> 3);
        const int c = t & 7;
        j = (c < 4) ? c : (2040 + c);
    } else return;
    scalar_point(i, j, x, poles, w_inner, w_east, w_cn, w_ne, w_nne,
                 w_nw, w_nww, w_west, out);
}

extern "C" void kernel_launch(void* const* d_in, const int* in_sizes, int n_in,
                              void* d_out, int out_size, void* d_ws, size_t ws_size,
                              hipStream_t stream) {
    const float* x       = (const float*)d_in[0];
    const float* poles   = (const float*)d_in[1];
    const float* w_inner = (const float*)d_in[2];
    const float* w_east  = (const float*)d_in[3];
    const float* w_cn    = (const float*)d_in[4];
    const float* w_ne    = (const float*)d_in[5];
    const float* w_nne   = (const float*)d_in[6];
    const float* w_nw    = (const float*)d_in[7];
    const float* w_nww   = (const float*)d_in[8];
    const float* w_west  = (const float*)d_in[9];
    float* out = (float*)d_out;

    dim3 grid(EDGE_BLOCKS + 2048), block(256);
    hipLaunchKernelGGL(icok, grid, block, 0, stream,
                       x, poles, w_inner, w_east, w_cn, w_ne, w_nne, w_nw,
                       w_nww, w_west, out);
}